// Round 6
// baseline (81.103 us; speedup 1.0000x reference)
//
#include <hip/hip_runtime.h>
#include <hip/hip_bf16.h>

typedef __attribute__((ext_vector_type(8))) short s16x8;
typedef __attribute__((ext_vector_type(4))) float f32x4;

#define NEGC 1000000000000.0f

constexpr int B_ = 8, S_ = 512, H_ = 768;
constexpr int ENT = 12, ARG = 16;
constexpr int NC = 320;              // 128 + 24 + 128 + 32 = 312, padded to 320
constexpr int ROWS = B_ * S_;        // 4096
constexpr size_t OUT_ENT = (size_t)B_ * ENT * S_ * S_;  // 25,165,824

static __device__ __forceinline__ unsigned short f2bf(float x) {
  return __builtin_bit_cast(unsigned short, __float2bfloat16(x));
}
static __device__ __forceinline__ float bf2f(unsigned short u) {
  return __builtin_bit_cast(float, (unsigned int)u << 16);
}

// ---------------------------------------------------------------------------
// Kernel 1: EXACT round-5 prep — full-grid. X->bf16 (float4), transposed
// concat weight Wt[320][768] bf16 (scalar gather), bias bcat[320].
// ---------------------------------------------------------------------------
__global__ __launch_bounds__(256) void k_prep(
    const float* __restrict__ X,
    const float* __restrict__ W1, const float* __restrict__ b1,
    const float* __restrict__ W2, const float* __restrict__ b2,
    const float* __restrict__ Wa1, const float* __restrict__ ba1,
    const float* __restrict__ Wa2, const float* __restrict__ ba2,
    __hip_bfloat16* __restrict__ Xb,
    __hip_bfloat16* __restrict__ Wt,
    float* __restrict__ bcat) {
  int idx = blockIdx.x * 256 + threadIdx.x;
  const int nx = ROWS * H_ / 4;  // 786432 float4 tasks
  if (idx < nx) {
    float4 v = reinterpret_cast<const float4*>(X)[idx];
    ushort4 o;
    o.x = f2bf(v.x); o.y = f2bf(v.y); o.z = f2bf(v.z); o.w = f2bf(v.w);
    reinterpret_cast<ushort4*>(Xb)[idx] = o;
    return;
  }
  idx -= nx;
  if (idx < NC * H_) {
    int n = idx / H_;
    int k = idx - n * H_;
    float v = 0.0f;
    if (n < 128)      v = W1[k * 128 + n];
    else if (n < 152) v = W2[k * 24 + (n - 128)];
    else if (n < 280) v = Wa1[k * 128 + (n - 152)];
    else if (n < 312) v = Wa2[k * 32 + (n - 280)];
    reinterpret_cast<unsigned short*>(Wt)[(size_t)n * H_ + k] = f2bf(v);
    return;
  }
  idx -= NC * H_;
  if (idx < NC) {
    int n = idx;
    float v = 0.0f;
    if (n < 128)      v = b1[n];
    else if (n < 152) v = b2[n - 128];
    else if (n < 280) v = ba1[n - 152];
    else if (n < 312) v = ba2[n - 280];
    bcat[n] = v;
  }
}

// ---------------------------------------------------------------------------
// Kernel 2: fused GEMM + bias + RoPE + bias-plane extraction (identical to
// round 5).
// ---------------------------------------------------------------------------
__global__ __launch_bounds__(256) void k_gemm(
    const __hip_bfloat16* __restrict__ Xb,
    const __hip_bfloat16* __restrict__ Wt,
    const float* __restrict__ bcat,
    __hip_bfloat16* __restrict__ qwe, __hip_bfloat16* __restrict__ kwe,
    __hip_bfloat16* __restrict__ qwa, __hip_bfloat16* __restrict__ kwa,
    float* __restrict__ kbe, float* __restrict__ qbe,
    float* __restrict__ kba, float* __restrict__ qba) {
  const int lane = threadIdx.x & 63;
  const int wid  = threadIdx.x >> 6;
  const int row0 = blockIdx.y * 64 + (wid >> 1) * 32;  // m (X rows)
  const int col0 = blockIdx.x * 64 + (wid & 1) * 32;   // n (P cols)
  const int rl   = lane & 15;
  const int rg   = lane >> 4;
  const int kseg = rg * 8;
  const short* Ws = reinterpret_cast<const short*>(Wt);
  const short* Xs = reinterpret_cast<const short*>(Xb);
  f32x4 acc[2][2] = {};  // [ni][mj]: quad = n, lane&15 = m
#pragma unroll 4
  for (int kk = 0; kk < H_; kk += 32) {
    s16x8 a[2], bb[2];
#pragma unroll
    for (int ni = 0; ni < 2; ++ni)
      a[ni] = *reinterpret_cast<const s16x8*>(Ws + (size_t)(col0 + ni * 16 + rl) * H_ + kk + kseg);
#pragma unroll
    for (int mj = 0; mj < 2; ++mj)
      bb[mj] = *reinterpret_cast<const s16x8*>(Xs + (size_t)(row0 + mj * 16 + rl) * H_ + kk + kseg);
#pragma unroll
    for (int ni = 0; ni < 2; ++ni)
#pragma unroll
      for (int mj = 0; mj < 2; ++mj)
        acc[ni][mj] = __builtin_amdgcn_mfma_f32_16x16x32_bf16(a[ni], bb[mj], acc[ni][mj], 0, 0, 0);
  }
#pragma unroll
  for (int ni = 0; ni < 2; ++ni) {
    const int nq = col0 + ni * 16 + rg * 4;
    if (nq >= 312) continue;
    float4 bc = *reinterpret_cast<const float4*>(bcat + nq);
#pragma unroll
    for (int mj = 0; mj < 2; ++mj) {
      const int r = row0 + mj * 16 + rl;  // global row
      const int b = r >> 9, mm = r & 511;
      float v0 = acc[ni][mj][0] + bc.x;
      float v1 = acc[ni][mj][1] + bc.y;
      float v2 = acc[ni][mj][2] + bc.z;
      float v3 = acc[ni][mj][3] + bc.w;
      if (nq < 128 || (nq >= 152 && nq < 280)) {
        const bool ent = nq < 128;
        const int p = (ent ? nq : nq - 152) >> 2;
        float inv = exp2f(-(float)p * 0.4152410118609203f);
        float s, c;
        sincosf((float)mm * inv, &s, &c);
        unsigned int qpk = (unsigned int)f2bf(v0 * c - v2 * s) |
                           ((unsigned int)f2bf(v2 * c + v0 * s) << 16);
        unsigned int kpk = (unsigned int)f2bf(v1 * c - v3 * s) |
                           ((unsigned int)f2bf(v3 * c + v1 * s) << 16);
        short* qd = reinterpret_cast<short*>(ent ? qwe : qwa);
        short* kd = reinterpret_cast<short*>(ent ? kwe : kwa);
        *reinterpret_cast<unsigned int*>(qd + (size_t)r * 64 + 2 * p) = qpk;
        *reinterpret_cast<unsigned int*>(kd + (size_t)r * 64 + 2 * p) = kpk;
      } else {
        const bool ent = nq < 152;
        const int base = ent ? 128 : 280;
        const int T = ent ? ENT : ARG;
        float* qb = ent ? qbe : qba;
        float* kb = ent ? kbe : kba;
        float vv[4] = {v0, v1, v2, v3};
#pragma unroll
        for (int q = 0; q < 4; ++q) {
          int e = nq - base + q;
          int t = e >> 1;
          float* dst = (e & 1) ? qb : kb;
          dst[((size_t)b * T + t) * S_ + mm] = vv[q] * 0.5f;
        }
      }
    }
  }
}

// ---------------------------------------------------------------------------
// Kernel 3 (NEW): row-streaming broadcast-write.
// Block = (t-chunk of 4 planes, 32-row m-slab, b); grid 7x16x8 = 896 blocks.
// Phase 1: qk[32][512] (x0.125) for this head -> LDS bf16 (33KB, 4 blk/CU).
// Phase 2: wave owns 8 consecutive rows; per (row, plane) writes the full
// 2KB output row as two 1KB-contiguous dwordx4 wave-stores.
// ---------------------------------------------------------------------------
__global__ __launch_bounds__(256) void k_bcast(
    const __hip_bfloat16* __restrict__ qwe, const __hip_bfloat16* __restrict__ kwe,
    const __hip_bfloat16* __restrict__ qwa, const __hip_bfloat16* __restrict__ kwa,
    const float* __restrict__ kbe, const float* __restrict__ qbe,
    const float* __restrict__ kba, const float* __restrict__ qba,
    const int* __restrict__ mask,
    float* __restrict__ out) {
  __shared__ unsigned short qk_lds[32][520];  // stride 1040B = 65*16B
  const int tid  = threadIdx.x;
  const int lane = tid & 63;
  const int w    = tid >> 6;
  const int b    = blockIdx.z;
  const int m0   = blockIdx.y * 32;
  const int c    = blockIdx.x;
  const bool ent = c < 3;
  const int t0   = (ent ? c : c - 3) * 4;
  const int T    = ent ? ENT : ARG;
  const short* qs = reinterpret_cast<const short*>(ent ? qwe : qwa);
  const short* ks = reinterpret_cast<const short*>(ent ? kwe : kwa);
  const float* qb = ent ? qbe : qba;
  const float* kb = ent ? kbe : kba;
  const size_t obase0 = ent ? (size_t)b * ENT * S_ * S_
                            : OUT_ENT + (size_t)b * ARG * S_ * S_;

  // ---- Phase 1: wave (mf = w&1, nh = w>>1) computes 16m x 256n of qk ----
  {
    const int cl = lane & 15, rg = lane >> 4, kseg = rg * 8;
    const int mf = w & 1, nh = w >> 1;
    const size_t qrow = (size_t)(b * S_ + m0 + mf * 16 + cl) * 64;
    s16x8 bq0 = *reinterpret_cast<const s16x8*>(qs + qrow + kseg);
    s16x8 bq1 = *reinterpret_cast<const s16x8*>(qs + qrow + 32 + kseg);
#pragma unroll
    for (int g = 0; g < 2; ++g) {
      f32x4 acc[8];
#pragma unroll
      for (int f = 0; f < 8; ++f) {
        const int n = nh * 256 + (g * 8 + f) * 16;
        const size_t krow = (size_t)(b * S_ + n + cl) * 64;
        s16x8 ak0 = *reinterpret_cast<const s16x8*>(ks + krow + kseg);
        s16x8 ak1 = *reinterpret_cast<const s16x8*>(ks + krow + 32 + kseg);
        f32x4 z = {};
        acc[f] = __builtin_amdgcn_mfma_f32_16x16x32_bf16(ak0, bq0, z, 0, 0, 0);
        acc[f] = __builtin_amdgcn_mfma_f32_16x16x32_bf16(ak1, bq1, acc[f], 0, 0, 0);
      }
#pragma unroll
      for (int f = 0; f < 8; ++f) {
        const int n = nh * 256 + (g * 8 + f) * 16 + rg * 4;
        ushort4 o;
        o.x = f2bf(acc[f][0] * 0.125f);
        o.y = f2bf(acc[f][1] * 0.125f);
        o.z = f2bf(acc[f][2] * 0.125f);
        o.w = f2bf(acc[f][3] * 0.125f);
        *reinterpret_cast<ushort4*>(&qk_lds[mf * 16 + cl][n]) = o;
      }
    }
  }
  __syncthreads();

  // ---- Phase 2: wave owns rows w*8 .. w*8+7; stream 4 planes ----
  const int nA = lane * 4;        // first-half cols
  const int nB = 256 + lane * 4;  // second-half cols
  const int* mp = mask + b * S_;
  float mkA[4], mkB[4], skA[4], skB[4];
#pragma unroll
  for (int i = 0; i < 4; ++i) {
    mkA[i] = (float)mp[nA + i];
    skA[i] = NEGC * (1.0f - mkA[i]);
    mkB[i] = (float)mp[nB + i];
    skB[i] = NEGC * (1.0f - mkB[i]);
  }
  float kvA[4][4], kvB[4][4];
#pragma unroll
  for (int t = 0; t < 4; ++t) {
    const float* kbp = kb + ((size_t)b * T + t0 + t) * S_;
    f32x4 a = *reinterpret_cast<const f32x4*>(kbp + nA);
    f32x4 bb = *reinterpret_cast<const f32x4*>(kbp + nB);
#pragma unroll
    for (int i = 0; i < 4; ++i) { kvA[t][i] = a[i]; kvB[t][i] = bb[i]; }
  }

  for (int rr = 0; rr < 8; ++rr) {
    const int r = w * 8 + rr;
    const int rglob = m0 + r;
    const float mq = (float)mp[rglob];
    const float sq = NEGC * (1.0f - mq);
    ushort4 ua = *reinterpret_cast<const ushort4*>(&qk_lds[r][nA]);
    ushort4 ub = *reinterpret_cast<const ushort4*>(&qk_lds[r][nB]);
    float qkA[4] = {bf2f(ua.x), bf2f(ua.y), bf2f(ua.z), bf2f(ua.w)};
    float qkB[4] = {bf2f(ub.x), bf2f(ub.y), bf2f(ub.z), bf2f(ub.w)};
    float MA[4], nOA[4], MB[4], nOB[4];
#pragma unroll
    for (int i = 0; i < 4; ++i) {
      MA[i]  = mq * mkA[i];
      nOA[i] = -(sq * mkA[i] + skA[i] + ((nA + i < rglob) ? NEGC : 0.0f));
      MB[i]  = mq * mkB[i];
      nOB[i] = -(sq * mkB[i] + skB[i] + ((nB + i < rglob) ? NEGC : 0.0f));
    }
#pragma unroll
    for (int t = 0; t < 4; ++t) {
      const float qv = qb[((size_t)b * T + t0 + t) * S_ + rglob];
      f32x4 vA, vB;
#pragma unroll
      for (int i = 0; i < 4; ++i) {
        vA[i] = fmaf(qkA[i] + (kvA[t][i] + qv), MA[i], nOA[i]);
        vB[i] = fmaf(qkB[i] + (kvB[t][i] + qv), MB[i], nOB[i]);
      }
      float* op = out + obase0 + (size_t)(t0 + t) * S_ * S_ + (size_t)rglob * S_;
      *reinterpret_cast<f32x4*>(op + nA) = vA;
      *reinterpret_cast<f32x4*>(op + nB) = vB;
    }
  }
}

// ---------------------------------------------------------------------------
extern "C" void kernel_launch(void* const* d_in, const int* in_sizes, int n_in,
                              void* d_out, int out_size, void* d_ws, size_t ws_size,
                              hipStream_t stream) {
  (void)in_sizes; (void)n_in; (void)out_size; (void)ws_size;
  const float* X   = (const float*)d_in[0];
  const int* mask  = (const int*)d_in[1];
  const float* W1  = (const float*)d_in[2];
  const float* b1  = (const float*)d_in[3];
  const float* W2  = (const float*)d_in[4];
  const float* b2  = (const float*)d_in[5];
  const float* Wa1 = (const float*)d_in[6];
  const float* ba1 = (const float*)d_in[7];
  const float* Wa2 = (const float*)d_in[8];
  const float* ba2 = (const float*)d_in[9];
  float* out = (float*)d_out;

  char* ws = (char*)d_ws;
  size_t off = 0;
  auto walloc = [&](size_t bytes) -> void* {
    void* p = ws + off;
    off += (bytes + 255) & ~(size_t)255;
    return p;
  };
  __hip_bfloat16* Xb  = (__hip_bfloat16*)walloc((size_t)ROWS * H_ * 2);
  __hip_bfloat16* Wt  = (__hip_bfloat16*)walloc((size_t)NC * H_ * 2);
  float* bcat         = (float*)walloc((size_t)NC * 4);
  __hip_bfloat16* qwe = (__hip_bfloat16*)walloc((size_t)ROWS * 64 * 2);
  __hip_bfloat16* kwe = (__hip_bfloat16*)walloc((size_t)ROWS * 64 * 2);
  __hip_bfloat16* qwa = (__hip_bfloat16*)walloc((size_t)ROWS * 64 * 2);
  __hip_bfloat16* kwa = (__hip_bfloat16*)walloc((size_t)ROWS * 64 * 2);
  float* kbe = (float*)walloc((size_t)B_ * ENT * S_ * 4);
  float* qbe = (float*)walloc((size_t)B_ * ENT * S_ * 4);
  float* kba = (float*)walloc((size_t)B_ * ARG * S_ * 4);
  float* qba = (float*)walloc((size_t)B_ * ARG * S_ * 4);

  const int prep_tasks = ROWS * H_ / 4 + NC * H_ + NC;
  k_prep<<<dim3((prep_tasks + 255) / 256), dim3(256), 0, stream>>>(
      X, W1, b1, W2, b2, Wa1, ba1, Wa2, ba2, Xb, Wt, bcat);
  k_gemm<<<dim3(NC / 64, ROWS / 64), dim3(256), 0, stream>>>(
      Xb, Wt, bcat, qwe, kwe, qwa, kwa, kbe, qbe, kba, qba);
  k_bcast<<<dim3(7, 16, 8), dim3(256), 0, stream>>>(
      qwe, kwe, qwa, kwa, kbe, qbe, kba, qba, mask, out);
}